// Round 3
// baseline (228.050 us; speedup 1.0000x reference)
//
#include <hip/hip_runtime.h>
#include <stdint.h>

#define N_NODES 30000
#define NC 256

typedef _Float16 f16x8 __attribute__((ext_vector_type(8)));
typedef _Float16 f16x4 __attribute__((ext_vector_type(4)));
typedef _Float16 f16x2 __attribute__((ext_vector_type(2)));
typedef float f32x4 __attribute__((ext_vector_type(4)));

// ---- convert W = [w_real; w_imag] ([512][256]) to f16 ----
__global__ void k_conv_w(const float* __restrict__ wr, const float* __restrict__ wi,
                         _Float16* __restrict__ Wb) {
    int i = (blockIdx.x * 256 + threadIdx.x) * 4;   // total 131,072 -> 128 blocks
    const float* src = (i < NC * NC) ? (wr + i) : (wi + (i - NC * NC));
    float4 v = *reinterpret_cast<const float4*>(src);
    f16x4 o;
    o[0] = (_Float16)v.x; o[1] = (_Float16)v.y;
    o[2] = (_Float16)v.z; o[3] = (_Float16)v.w;
    *reinterpret_cast<f16x4*>(Wb + i) = o;
}

// ---- GEMM: h = clip(x) @ [wr;wi]^T + bias, f16 MFMA, fused f32->f16 on A ----
// Block bn owns channels [bn*64, bn*64+64): wave wn=0 computes re, wn=1 im.
// => every 64B line of H is fully written by ONE block (kills R2's 2.5x
//    write amplification: re came from bn, im from bn+2, L2 couldn't merge).
// K-loop is 2-deep register double-buffered (R2: MfmaUtil 4.3% = latency-bound).
__global__ __launch_bounds__(256) void k_gemm(
    const float* __restrict__ X, const _Float16* __restrict__ B,
    const float* __restrict__ br, const float* __restrict__ bi,
    _Float16* __restrict__ H)
{
    int bid = blockIdx.x;
    int bm = bid >> 2, bn = bid & 3;          // 235 x 4 blocks
    int tid = threadIdx.x;
    int lane = tid & 63, wave = tid >> 6;
    int quad = lane >> 4, l16 = lane & 15;
    int wm = wave >> 1, wn = wave & 1;
    int row0 = bm * 128 + wm * 64;
    int cbase = bn * 64;                      // channel base for this block
    int brow0 = (wn ? 256 : 0) + cbase;       // row base in Wb for this wave

    const float* xp[4];
    const _Float16* bp[4];
#pragma unroll
    for (int mi = 0; mi < 4; mi++) {
        int r = row0 + mi * 16 + l16;
        if (r >= N_NODES) r = N_NODES - 1;    // clamp: garbage rows never stored
        xp[mi] = X + r * NC + quad * 8;
    }
#pragma unroll
    for (int ni = 0; ni < 4; ni++)
        bp[ni] = B + (brow0 + ni * 16 + l16) * NC + quad * 8;

    f32x4 acc[4][4] = {};
    f16x8 a0[4], b0[4], a1[4], b1[4];

    auto loadA = [&](f16x8* dst, int k) {
#pragma unroll
        for (int mi = 0; mi < 4; mi++) {
            float4 u = *reinterpret_cast<const float4*>(xp[mi] + k);
            float4 v = *reinterpret_cast<const float4*>(xp[mi] + k + 4);
            f16x8 t;
            t[0] = (_Float16)fminf(fmaxf(u.x, -10.f), 10.f);
            t[1] = (_Float16)fminf(fmaxf(u.y, -10.f), 10.f);
            t[2] = (_Float16)fminf(fmaxf(u.z, -10.f), 10.f);
            t[3] = (_Float16)fminf(fmaxf(u.w, -10.f), 10.f);
            t[4] = (_Float16)fminf(fmaxf(v.x, -10.f), 10.f);
            t[5] = (_Float16)fminf(fmaxf(v.y, -10.f), 10.f);
            t[6] = (_Float16)fminf(fmaxf(v.z, -10.f), 10.f);
            t[7] = (_Float16)fminf(fmaxf(v.w, -10.f), 10.f);
            dst[mi] = t;
        }
    };
    auto loadB = [&](f16x8* dst, int k) {
#pragma unroll
        for (int ni = 0; ni < 4; ni++)
            dst[ni] = *reinterpret_cast<const f16x8*>(bp[ni] + k);
    };
    auto domfma = [&](f16x8* a, f16x8* b) {
#pragma unroll
        for (int mi = 0; mi < 4; mi++)
#pragma unroll
            for (int ni = 0; ni < 4; ni++)
                acc[mi][ni] = __builtin_amdgcn_mfma_f32_16x16x32_f16(
                    a[mi], b[ni], acc[mi][ni], 0, 0, 0);
    };

    loadA(a0, 0); loadB(b0, 0);
#pragma unroll
    for (int kk = 0; kk < NC; kk += 64) {
        if (kk + 32 < NC) { loadA(a1, kk + 32); loadB(b1, kk + 32); }
        domfma(a0, b0);
        if (kk + 64 < NC) { loadA(a0, kk + 64); loadB(b0, kk + 64); }
        domfma(a1, b1);
    }

    const float* bias_p = wn ? bi : br;
#pragma unroll
    for (int ni = 0; ni < 4; ni++) {
        int c = cbase + ni * 16 + l16;
        float bias = bias_p[c];
        int cc = 2 * c + wn;                  // interleaved (re,im) per channel
#pragma unroll
        for (int mi = 0; mi < 4; mi++) {
            int rowb = row0 + mi * 16 + quad * 4;
#pragma unroll
            for (int r = 0; r < 4; r++) {
                int row = rowb + r;
                if (row < N_NODES) H[row * 512 + cc] = (_Float16)(acc[mi][ni][r] + bias);
            }
        }
    }
}

// ---- evolve: out = x + esc*(h[i] - i*sum_s g_s h[n_s]); accumulate mag stats ----
#define NPB 30
__global__ __launch_bounds__(256) void k_evolve(
    const float* __restrict__ x, const int* __restrict__ sub_nodes,
    const float* __restrict__ sub_mask, const float* __restrict__ subH,
    const _Float16* __restrict__ h, const float* __restrict__ escp,
    float* __restrict__ outz, _Float16* __restrict__ zbuf, int use_f16,
    float* __restrict__ ssum, float* __restrict__ ssumsq)
{
    __shared__ int   s_nodes[NPB][4];
    __shared__ float s_g[NPB][4];
    __shared__ float s_m0[NPB];
    int tid = threadIdx.x;
    int base = blockIdx.x * NPB;      // 30000 = 1000*30 exactly
    if (tid < NPB) {
        int node = base + tid;
        float fr = 0.f;
#pragma unroll
        for (int t = 0; t < 16; t++) { float v = subH[node * 16 + t]; fr += v * v; }
        // A = -i * H * 1e-4/||H||_F  (eigen- and norm-clamps provably always fire
        // and their scalar factors cancel; Taylor >=2nd order terms are <=5e-9)
        float coef = 1e-4f * rsqrtf(fr);
#pragma unroll
        for (int s = 0; s < 4; s++) {
            s_g[tid][s]     = coef * subH[node * 16 + s] * sub_mask[node * 4 + s];
            s_nodes[tid][s] = sub_nodes[node * 4 + s];
        }
        s_m0[tid] = sub_mask[node * 4];
    }
    __syncthreads();
    float esc = *escp;
    float lsum = 0.f, lsq = 0.f;
    for (int j = 0; j < NPB; j++) {
        int node = base + j;
        float evr = 0.f, evi = 0.f;
#pragma unroll
        for (int s = 0; s < 4; s++) {
            int ns = s_nodes[j][s];
            float g = s_g[j][s];
            f16x2 v = *reinterpret_cast<const f16x2*>(h + ns * 512 + tid * 2);
            float hr = (float)v[0], hi = (float)v[1];
            evr += g * hi;           // -i*g*(hr + i*hi) = g*hi - i*g*hr
            evi -= g * hr;
            if (s == 0) { float m0 = s_m0[j]; evr += m0 * hr; evi += m0 * hi; }
        }
        float xr = x[node * NC + tid];
        float outr = fmaf(esc, evr, xr);
        float outi = esc * evi;
        if (use_f16) {
            f16x2 o; o[0] = (_Float16)outr; o[1] = (_Float16)outi;
            *reinterpret_cast<f16x2*>(zbuf + node * 512 + tid * 2) = o;
        } else {
            outz[node * 512 + tid] = outr;
            outz[node * 512 + 256 + tid] = outi;
        }
        float mag = sqrtf(fmaf(outr, outr, fmaf(outi, outi, 1e-5f)));
        mag = fminf(fmaxf(mag, 1e-5f), 1000.f);
        lsum += mag;
        lsq = fmaf(mag, mag, lsq);
    }
    atomicAdd(&ssum[tid], lsum);     // tid == channel; 1000 adds per address
    atomicAdd(&ssumsq[tid], lsq);
}

// ---- layernorm + phase + leaky crelu; stats affine recomputed inline ----
// (k_stats folded in: removes a 1-block serialization bubble)
__global__ __launch_bounds__(256) void k_norm(
    float* __restrict__ out, const _Float16* __restrict__ zbuf, int use_f16,
    const float* __restrict__ ssum, const float* __restrict__ ssumsq,
    const float* __restrict__ lnw, const float* __restrict__ lnb)
{
    int tid = threadIdx.x;
    int node = blockIdx.x * 4 + (tid >> 6);        // 7500 blocks
    int c0 = (tid & 63) * 4;
    float re[4], im[4];
    if (use_f16) {
        f16x8 z = *reinterpret_cast<const f16x8*>(zbuf + node * 512 + c0 * 2);
#pragma unroll
        for (int e = 0; e < 4; e++) { re[e] = (float)z[2 * e]; im[e] = (float)z[2 * e + 1]; }
    } else {
        float4 r4 = *reinterpret_cast<const float4*>(out + node * 512 + c0);
        float4 i4 = *reinterpret_cast<const float4*>(out + node * 512 + 256 + c0);
        re[0] = r4.x; re[1] = r4.y; re[2] = r4.z; re[3] = r4.w;
        im[0] = i4.x; im[1] = i4.y; im[2] = i4.z; im[3] = i4.w;
    }
    float4 s4 = *reinterpret_cast<const float4*>(ssum + c0);
    float4 q4 = *reinterpret_cast<const float4*>(ssumsq + c0);
    float4 w4 = *reinterpret_cast<const float4*>(lnw + c0);
    float4 lb4 = *reinterpret_cast<const float4*>(lnb + c0);
    float S[4] = {s4.x, s4.y, s4.z, s4.w};
    float Q[4] = {q4.x, q4.y, q4.z, q4.w};
    float W[4] = {w4.x, w4.y, w4.z, w4.w};
    float L[4] = {lb4.x, lb4.y, lb4.z, lb4.w};
    const float invN = 1.0f / (float)N_NODES;
    float orr[4], oii[4];
#pragma unroll
    for (int e = 0; e < 4; e++) {
        float mean = S[e] * invN;
        float var = fmaxf(Q[e] * invN - mean * mean, 0.f);
        float denom = sqrtf(var + 1e-5f) + 1e-5f;
        float A = fabsf(W[e]) / denom;
        float Bc = L[e] - mean * A;
        float r = re[e], i = im[e];
        float mag = sqrtf(fmaf(r, r, fmaf(i, i, 1e-5f)));
        mag = fminf(fmaxf(mag, 1e-5f), 1000.f);
        float sm = fmaf(mag, A, Bc);
        sm = fminf(fmaxf(sm, 1e-5f), 10.0f);
        float px = fminf(fmaxf(r, -1e6f), 1e6f) + 1e-10f;
        float py = fminf(fmaxf(i, -1e6f), 1e6f);
        float r2 = fmaf(px, px, py * py);
        float inv = rsqrtf(r2);
        float zr = sm * px * inv, zi = sm * py * inv;
        zr = fminf(fmaxf(zr, -5.f), 5.f);
        zi = fminf(fmaxf(zi, -5.f), 5.f);
        orr[e] = zr > 0.f ? zr : 0.01f * zr;
        oii[e] = zi > 0.f ? zi : 0.01f * zi;
    }
    *reinterpret_cast<float4*>(out + node * 512 + c0) =
        make_float4(orr[0], orr[1], orr[2], orr[3]);
    *reinterpret_cast<float4*>(out + node * 512 + 256 + c0) =
        make_float4(oii[0], oii[1], oii[2], oii[3]);
}

extern "C" void kernel_launch(void* const* d_in, const int* in_sizes, int n_in,
                              void* d_out, int out_size, void* d_ws, size_t ws_size,
                              hipStream_t stream) {
    const float* x        = (const float*)d_in[0];
    // d_in[1] edge_index: unused (sub_nodes/sub_mask/sub_H are precomputed)
    const int*   sub_nodes = (const int*)d_in[2];
    const float* sub_mask  = (const float*)d_in[3];
    const float* subH      = (const float*)d_in[4];
    const float* wr  = (const float*)d_in[5];
    const float* wi  = (const float*)d_in[6];
    const float* br  = (const float*)d_in[7];
    const float* bi  = (const float*)d_in[8];
    const float* lnw = (const float*)d_in[9];
    const float* lnb = (const float*)d_in[10];
    const float* esc = (const float*)d_in[11];
    float* out = (float*)d_out;

    char* ws = (char*)d_ws;
    const size_t WB_OFF   = 0;                    // 512*256*2    =    262,144
    const size_t H_OFF    = 262144;               // 30000*512*2  = 30,720,000
    const size_t STAT_OFF = 30982144;             // 4 * 1024
    const size_t ZB_OFF   = 30986240;             // 30000*512*2  = 30,720,000 (optional)
    const size_t WS_NEED_F16 = ZB_OFF + 30720000; // 61,706,240
    _Float16* Wb = (_Float16*)(ws + WB_OFF);
    _Float16* h  = (_Float16*)(ws + H_OFF);
    float* ssum   = (float*)(ws + STAT_OFF);
    float* ssumsq = (float*)(ws + STAT_OFF + 1024);
    _Float16* zbuf = (_Float16*)(ws + ZB_OFF);
    int use_f16 = (ws_size >= WS_NEED_F16) ? 1 : 0;

    hipMemsetAsync(ssum, 0, 2048, stream);
    hipLaunchKernelGGL(k_conv_w, dim3(128), dim3(256), 0, stream, wr, wi, Wb);
    hipLaunchKernelGGL(k_gemm, dim3(235 * 4), dim3(256), 0, stream, x, Wb, br, bi, h);
    hipLaunchKernelGGL(k_evolve, dim3(1000), dim3(256), 0, stream,
                       x, sub_nodes, sub_mask, subH, h, esc, out, zbuf, use_f16,
                       ssum, ssumsq);
    hipLaunchKernelGGL(k_norm, dim3(7500), dim3(256), 0, stream,
                       out, zbuf, use_f16, ssum, ssumsq, lnw, lnb);
}

// Round 4
// 215.247 us; speedup vs baseline: 1.0595x; 1.0595x over previous
//
#include <hip/hip_runtime.h>
#include <stdint.h>

#define N_NODES 30000
#define NC 256

typedef _Float16 f16x8 __attribute__((ext_vector_type(8)));
typedef _Float16 f16x4 __attribute__((ext_vector_type(4)));
typedef _Float16 f16x2 __attribute__((ext_vector_type(2)));
typedef float f32x4 __attribute__((ext_vector_type(4)));

// ---- convert x (with clip +-10) to f16 ----
__global__ void k_conv_x(const float* __restrict__ x, _Float16* __restrict__ xb) {
    int i = (blockIdx.x * 256 + threadIdx.x) * 4;   // total 7,680,000 -> 7500 blocks
    float4 v = *reinterpret_cast<const float4*>(x + i);
    f16x4 o;
    o[0] = (_Float16)fminf(fmaxf(v.x, -10.f), 10.f);
    o[1] = (_Float16)fminf(fmaxf(v.y, -10.f), 10.f);
    o[2] = (_Float16)fminf(fmaxf(v.z, -10.f), 10.f);
    o[3] = (_Float16)fminf(fmaxf(v.w, -10.f), 10.f);
    *reinterpret_cast<f16x4*>(xb + i) = o;
}

// ---- convert W = [w_real; w_imag] ([512][256]) to f16 ----
__global__ void k_conv_w(const float* __restrict__ wr, const float* __restrict__ wi,
                         _Float16* __restrict__ Wb) {
    int i = (blockIdx.x * 256 + threadIdx.x) * 4;   // total 131,072 -> 128 blocks
    const float* src = (i < NC * NC) ? (wr + i) : (wi + (i - NC * NC));
    float4 v = *reinterpret_cast<const float4*>(src);
    f16x4 o;
    o[0] = (_Float16)v.x; o[1] = (_Float16)v.y;
    o[2] = (_Float16)v.z; o[3] = (_Float16)v.w;
    *reinterpret_cast<f16x4*>(Wb + i) = o;
}

// ---- GEMM v3: A held register-resident for full K ----
// R3 counters: MfmaUtil 4.3%, all pipes idle -> traffic-structure problem
// (~240 MB of per-wave redundant A loads vs 15.4 MB minimal). Here each wave
// loads its 32 A-frags (64 rows x K=256, f16, 128 VGPRs) ONCE, then streams
// 256 MFMAs against B (262 KB, L2-resident) double-buffered.
// Grid: bm(235) x cs(2); block = 128 rows x 128 channels (re+im via wn).
__global__ __launch_bounds__(256, 2) void k_gemm(
    const _Float16* __restrict__ A, const _Float16* __restrict__ B,
    const float* __restrict__ br, const float* __restrict__ bi,
    _Float16* __restrict__ H)
{
    int bid = blockIdx.x;
    int bm = bid >> 1, cs = bid & 1;          // 235 x 2 blocks
    int tid = threadIdx.x;
    int lane = tid & 63, wave = tid >> 6;
    int quad = lane >> 4, l16 = lane & 15;
    int wm = wave >> 1, wn = wave & 1;        // wm: row half, wn: re/im
    int row0 = bm * 128 + wm * 64;

    // ---- preload ALL A fragments for K=256 (32 x f16x8 = 128 VGPRs) ----
    f16x8 af[4][8];
#pragma unroll
    for (int mi = 0; mi < 4; mi++) {
        int r = row0 + mi * 16 + l16;
        if (r >= N_NODES) r = N_NODES - 1;    // clamp: garbage rows never stored
        const _Float16* ap = A + r * NC + quad * 8;
#pragma unroll
        for (int kc = 0; kc < 8; kc++)
            af[mi][kc] = *reinterpret_cast<const f16x8*>(ap + kc * 32);
    }

    const float* bias_p = wn ? bi : br;
#pragma unroll
    for (int cn = 0; cn < 2; cn++) {
        // B rows for this wave's 64 channels: [wn*256 + cs*128 + cn*64 ...)
        const _Float16* bbase = B + ((wn ? 256 : 0) + cs * 128 + cn * 64 + l16) * NC
                                  + quad * 8;
        f16x8 bb[2][4];
#pragma unroll
        for (int ni = 0; ni < 4; ni++)
            bb[0][ni] = *reinterpret_cast<const f16x8*>(bbase + ni * 16 * NC);
        f32x4 acc[4][4] = {};
#pragma unroll
        for (int kc = 0; kc < 8; kc++) {
            int cur = kc & 1, nxt = cur ^ 1;
            if (kc < 7) {
#pragma unroll
                for (int ni = 0; ni < 4; ni++)
                    bb[nxt][ni] = *reinterpret_cast<const f16x8*>(
                        bbase + ni * 16 * NC + (kc + 1) * 32);
            }
#pragma unroll
            for (int mi = 0; mi < 4; mi++)
#pragma unroll
                for (int ni = 0; ni < 4; ni++)
                    acc[mi][ni] = __builtin_amdgcn_mfma_f32_16x16x32_f16(
                        af[mi][kc], bb[cur][ni], acc[mi][ni], 0, 0, 0);
        }
        // epilogue: channel c -> interleaved slot 2c+wn (one block owns both
        // halves of each 64B line -> L2 merges; R3 verified WRITE ~30 MB)
#pragma unroll
        for (int ni = 0; ni < 4; ni++) {
            int c = cs * 128 + cn * 64 + ni * 16 + l16;
            float bias = bias_p[c];
            int cc = 2 * c + wn;
#pragma unroll
            for (int mi = 0; mi < 4; mi++) {
                int rowb = row0 + mi * 16 + quad * 4;
#pragma unroll
                for (int r = 0; r < 4; r++) {
                    int row = rowb + r;
                    if (row < N_NODES)
                        H[row * 512 + cc] = (_Float16)(acc[mi][ni][r] + bias);
                }
            }
        }
    }
}

// ---- evolve: out = x + esc*(h[i] - i*sum_s g_s h[n_s]); accumulate mag stats ----
#define NPB 30
__global__ __launch_bounds__(256) void k_evolve(
    const float* __restrict__ x, const int* __restrict__ sub_nodes,
    const float* __restrict__ sub_mask, const float* __restrict__ subH,
    const _Float16* __restrict__ h, const float* __restrict__ escp,
    float* __restrict__ outz, _Float16* __restrict__ zbuf, int use_f16,
    float* __restrict__ ssum, float* __restrict__ ssumsq)
{
    __shared__ int   s_nodes[NPB][4];
    __shared__ float s_g[NPB][4];
    __shared__ float s_m0[NPB];
    int tid = threadIdx.x;
    int base = blockIdx.x * NPB;      // 30000 = 1000*30 exactly
    if (tid < NPB) {
        int node = base + tid;
        float fr = 0.f;
#pragma unroll
        for (int t = 0; t < 16; t++) { float v = subH[node * 16 + t]; fr += v * v; }
        // A = -i * H * 1e-4/||H||_F  (eigen- and norm-clamps provably always fire
        // and their scalar factors cancel; Taylor >=2nd order terms are <=5e-9)
        float coef = 1e-4f * rsqrtf(fr);
#pragma unroll
        for (int s = 0; s < 4; s++) {
            s_g[tid][s]     = coef * subH[node * 16 + s] * sub_mask[node * 4 + s];
            s_nodes[tid][s] = sub_nodes[node * 4 + s];
        }
        s_m0[tid] = sub_mask[node * 4];
    }
    __syncthreads();
    float esc = *escp;
    float lsum = 0.f, lsq = 0.f;
    for (int j = 0; j < NPB; j++) {
        int node = base + j;
        float evr = 0.f, evi = 0.f;
#pragma unroll
        for (int s = 0; s < 4; s++) {
            int ns = s_nodes[j][s];
            float g = s_g[j][s];
            f16x2 v = *reinterpret_cast<const f16x2*>(h + ns * 512 + tid * 2);
            float hr = (float)v[0], hi = (float)v[1];
            evr += g * hi;           // -i*g*(hr + i*hi) = g*hi - i*g*hr
            evi -= g * hr;
            if (s == 0) { float m0 = s_m0[j]; evr += m0 * hr; evi += m0 * hi; }
        }
        float xr = x[node * NC + tid];
        float outr = fmaf(esc, evr, xr);
        float outi = esc * evi;
        if (use_f16) {
            f16x2 o; o[0] = (_Float16)outr; o[1] = (_Float16)outi;
            *reinterpret_cast<f16x2*>(zbuf + node * 512 + tid * 2) = o;
        } else {
            outz[node * 512 + tid] = outr;
            outz[node * 512 + 256 + tid] = outi;
        }
        float mag = sqrtf(fmaf(outr, outr, fmaf(outi, outi, 1e-5f)));
        mag = fminf(fmaxf(mag, 1e-5f), 1000.f);
        lsum += mag;
        lsq = fmaf(mag, mag, lsq);
    }
    atomicAdd(&ssum[tid], lsum);     // tid == channel; 1000 adds per address
    atomicAdd(&ssumsq[tid], lsq);
}

// ---- layernorm + phase + leaky crelu; stats affine recomputed inline ----
__global__ __launch_bounds__(256) void k_norm(
    float* __restrict__ out, const _Float16* __restrict__ zbuf, int use_f16,
    const float* __restrict__ ssum, const float* __restrict__ ssumsq,
    const float* __restrict__ lnw, const float* __restrict__ lnb)
{
    int tid = threadIdx.x;
    int node = blockIdx.x * 4 + (tid >> 6);        // 7500 blocks
    int c0 = (tid & 63) * 4;
    float re[4], im[4];
    if (use_f16) {
        f16x8 z = *reinterpret_cast<const f16x8*>(zbuf + node * 512 + c0 * 2);
#pragma unroll
        for (int e = 0; e < 4; e++) { re[e] = (float)z[2 * e]; im[e] = (float)z[2 * e + 1]; }
    } else {
        float4 r4 = *reinterpret_cast<const float4*>(out + node * 512 + c0);
        float4 i4 = *reinterpret_cast<const float4*>(out + node * 512 + 256 + c0);
        re[0] = r4.x; re[1] = r4.y; re[2] = r4.z; re[3] = r4.w;
        im[0] = i4.x; im[1] = i4.y; im[2] = i4.z; im[3] = i4.w;
    }
    float4 s4 = *reinterpret_cast<const float4*>(ssum + c0);
    float4 q4 = *reinterpret_cast<const float4*>(ssumsq + c0);
    float4 w4 = *reinterpret_cast<const float4*>(lnw + c0);
    float4 lb4 = *reinterpret_cast<const float4*>(lnb + c0);
    float S[4] = {s4.x, s4.y, s4.z, s4.w};
    float Q[4] = {q4.x, q4.y, q4.z, q4.w};
    float W[4] = {w4.x, w4.y, w4.z, w4.w};
    float L[4] = {lb4.x, lb4.y, lb4.z, lb4.w};
    const float invN = 1.0f / (float)N_NODES;
    float orr[4], oii[4];
#pragma unroll
    for (int e = 0; e < 4; e++) {
        float mean = S[e] * invN;
        float var = fmaxf(Q[e] * invN - mean * mean, 0.f);
        float denom = sqrtf(var + 1e-5f) + 1e-5f;
        float A = fabsf(W[e]) / denom;
        float Bc = L[e] - mean * A;
        float r = re[e], i = im[e];
        float mag = sqrtf(fmaf(r, r, fmaf(i, i, 1e-5f)));
        mag = fminf(fmaxf(mag, 1e-5f), 1000.f);
        float sm = fmaf(mag, A, Bc);
        sm = fminf(fmaxf(sm, 1e-5f), 10.0f);
        float px = fminf(fmaxf(r, -1e6f), 1e6f) + 1e-10f;
        float py = fminf(fmaxf(i, -1e6f), 1e6f);
        float r2 = fmaf(px, px, py * py);
        float inv = rsqrtf(r2);
        float zr = sm * px * inv, zi = sm * py * inv;
        zr = fminf(fmaxf(zr, -5.f), 5.f);
        zi = fminf(fmaxf(zi, -5.f), 5.f);
        orr[e] = zr > 0.f ? zr : 0.01f * zr;
        oii[e] = zi > 0.f ? zi : 0.01f * zi;
    }
    *reinterpret_cast<float4*>(out + node * 512 + c0) =
        make_float4(orr[0], orr[1], orr[2], orr[3]);
    *reinterpret_cast<float4*>(out + node * 512 + 256 + c0) =
        make_float4(oii[0], oii[1], oii[2], oii[3]);
}

extern "C" void kernel_launch(void* const* d_in, const int* in_sizes, int n_in,
                              void* d_out, int out_size, void* d_ws, size_t ws_size,
                              hipStream_t stream) {
    const float* x        = (const float*)d_in[0];
    // d_in[1] edge_index: unused (sub_nodes/sub_mask/sub_H are precomputed)
    const int*   sub_nodes = (const int*)d_in[2];
    const float* sub_mask  = (const float*)d_in[3];
    const float* subH      = (const float*)d_in[4];
    const float* wr  = (const float*)d_in[5];
    const float* wi  = (const float*)d_in[6];
    const float* br  = (const float*)d_in[7];
    const float* bi  = (const float*)d_in[8];
    const float* lnw = (const float*)d_in[9];
    const float* lnb = (const float*)d_in[10];
    const float* esc = (const float*)d_in[11];
    float* out = (float*)d_out;

    char* ws = (char*)d_ws;
    const size_t XB_OFF   = 0;                    // 30000*256*2  = 15,360,000
    const size_t WB_OFF   = 15360000;             // 512*256*2    =    262,144
    const size_t H_OFF    = 15622144;             // 30000*512*2  = 30,720,000
    const size_t STAT_OFF = 46342144;             // 4 * 1024
    const size_t ZB_OFF   = 46346240;             // 30000*512*2  = 30,720,000 (optional)
    const size_t WS_NEED_F16 = ZB_OFF + 30720000; // 77,066,240
    _Float16* xb = (_Float16*)(ws + XB_OFF);
    _Float16* Wb = (_Float16*)(ws + WB_OFF);
    _Float16* h  = (_Float16*)(ws + H_OFF);
    float* ssum   = (float*)(ws + STAT_OFF);
    float* ssumsq = (float*)(ws + STAT_OFF + 1024);
    _Float16* zbuf = (_Float16*)(ws + ZB_OFF);
    int use_f16 = (ws_size >= WS_NEED_F16) ? 1 : 0;

    hipMemsetAsync(ssum, 0, 2048, stream);
    hipLaunchKernelGGL(k_conv_x, dim3(7500), dim3(256), 0, stream, x, xb);
    hipLaunchKernelGGL(k_conv_w, dim3(128), dim3(256), 0, stream, wr, wi, Wb);
    hipLaunchKernelGGL(k_gemm, dim3(235 * 2), dim3(256), 0, stream, xb, Wb, br, bi, h);
    hipLaunchKernelGGL(k_evolve, dim3(1000), dim3(256), 0, stream,
                       x, sub_nodes, sub_mask, subH, h, esc, out, zbuf, use_f16,
                       ssum, ssumsq);
    hipLaunchKernelGGL(k_norm, dim3(7500), dim3(256), 0, stream,
                       out, zbuf, use_f16, ssum, ssumsq, lnw, lnb);
}

// Round 5
// 210.367 us; speedup vs baseline: 1.0841x; 1.0232x over previous
//
#include <hip/hip_runtime.h>
#include <stdint.h>

#define N_NODES 30000
#define NC 256

typedef _Float16 f16x8 __attribute__((ext_vector_type(8)));
typedef _Float16 f16x4 __attribute__((ext_vector_type(4)));
typedef _Float16 f16x2 __attribute__((ext_vector_type(2)));
typedef float f32x4 __attribute__((ext_vector_type(4)));

// ---- convert x (with clip +-10) to f16 ----
__global__ void k_conv_x(const float* __restrict__ x, _Float16* __restrict__ xb) {
    int i = (blockIdx.x * 256 + threadIdx.x) * 4;   // total 7,680,000 -> 7500 blocks
    float4 v = *reinterpret_cast<const float4*>(x + i);
    f16x4 o;
    o[0] = (_Float16)fminf(fmaxf(v.x, -10.f), 10.f);
    o[1] = (_Float16)fminf(fmaxf(v.y, -10.f), 10.f);
    o[2] = (_Float16)fminf(fmaxf(v.z, -10.f), 10.f);
    o[3] = (_Float16)fminf(fmaxf(v.w, -10.f), 10.f);
    *reinterpret_cast<f16x4*>(xb + i) = o;
}

// ---- convert W = [w_real; w_imag] ([512][256]) to f16 ----
__global__ void k_conv_w(const float* __restrict__ wr, const float* __restrict__ wi,
                         _Float16* __restrict__ Wb) {
    int i = (blockIdx.x * 256 + threadIdx.x) * 4;   // total 131,072 -> 128 blocks
    const float* src = (i < NC * NC) ? (wr + i) : (wi + (i - NC * NC));
    float4 v = *reinterpret_cast<const float4*>(src);
    f16x4 o;
    o[0] = (_Float16)v.x; o[1] = (_Float16)v.y;
    o[2] = (_Float16)v.z; o[3] = (_Float16)v.w;
    *reinterpret_cast<f16x4*>(Wb + i) = o;
}

// ---- GEMM v3: A held register-resident for full K (unchanged from R4) ----
__global__ __launch_bounds__(256, 2) void k_gemm(
    const _Float16* __restrict__ A, const _Float16* __restrict__ B,
    const float* __restrict__ br, const float* __restrict__ bi,
    _Float16* __restrict__ H)
{
    int bid = blockIdx.x;
    int bm = bid >> 1, cs = bid & 1;          // 235 x 2 blocks
    int tid = threadIdx.x;
    int lane = tid & 63, wave = tid >> 6;
    int quad = lane >> 4, l16 = lane & 15;
    int wm = wave >> 1, wn = wave & 1;        // wm: row half, wn: re/im
    int row0 = bm * 128 + wm * 64;

    f16x8 af[4][8];
#pragma unroll
    for (int mi = 0; mi < 4; mi++) {
        int r = row0 + mi * 16 + l16;
        if (r >= N_NODES) r = N_NODES - 1;    // clamp: garbage rows never stored
        const _Float16* ap = A + r * NC + quad * 8;
#pragma unroll
        for (int kc = 0; kc < 8; kc++)
            af[mi][kc] = *reinterpret_cast<const f16x8*>(ap + kc * 32);
    }

    const float* bias_p = wn ? bi : br;
#pragma unroll
    for (int cn = 0; cn < 2; cn++) {
        const _Float16* bbase = B + ((wn ? 256 : 0) + cs * 128 + cn * 64 + l16) * NC
                                  + quad * 8;
        f16x8 bb[2][4];
#pragma unroll
        for (int ni = 0; ni < 4; ni++)
            bb[0][ni] = *reinterpret_cast<const f16x8*>(bbase + ni * 16 * NC);
        f32x4 acc[4][4] = {};
#pragma unroll
        for (int kc = 0; kc < 8; kc++) {
            int cur = kc & 1, nxt = cur ^ 1;
            if (kc < 7) {
#pragma unroll
                for (int ni = 0; ni < 4; ni++)
                    bb[nxt][ni] = *reinterpret_cast<const f16x8*>(
                        bbase + ni * 16 * NC + (kc + 1) * 32);
            }
#pragma unroll
            for (int mi = 0; mi < 4; mi++)
#pragma unroll
                for (int ni = 0; ni < 4; ni++)
                    acc[mi][ni] = __builtin_amdgcn_mfma_f32_16x16x32_f16(
                        af[mi][kc], bb[cur][ni], acc[mi][ni], 0, 0, 0);
        }
#pragma unroll
        for (int ni = 0; ni < 4; ni++) {
            int c = cs * 128 + cn * 64 + ni * 16 + l16;
            float bias = bias_p[c];
            int cc = 2 * c + wn;
#pragma unroll
            for (int mi = 0; mi < 4; mi++) {
                int rowb = row0 + mi * 16 + quad * 4;
#pragma unroll
                for (int r = 0; r < 4; r++) {
                    int row = rowb + r;
                    if (row < N_NODES)
                        H[row * 512 + cc] = (_Float16)(acc[mi][ni][r] + bias);
                }
            }
        }
    }
}

// ---- evolve v2: 4 channels/lane, 16B loads ----
// R4 counters: dur 48.6us, HBM 27%, VALUBusy 19%, Occ 29% -> latency-bound on
// issue count: 150 independent 4B loads/thread. Here: 4 ch/lane via f16x8
// gathers (1/4 the loads, same bytes, still 1KB/wave coalesced). Group g
// (tid>>6) processes nodes j=g,g+4,.. of the block's 30; stats reduced across
// groups in LDS -> 1 atomic per channel per block.
#define NPB 30
__global__ __launch_bounds__(256) void k_evolve(
    const float* __restrict__ x, const int* __restrict__ sub_nodes,
    const float* __restrict__ sub_mask, const float* __restrict__ subH,
    const _Float16* __restrict__ h, const float* __restrict__ escp,
    float* __restrict__ outz, _Float16* __restrict__ zbuf, int use_f16,
    float* __restrict__ ssum, float* __restrict__ ssumsq)
{
    __shared__ int   s_nodes[NPB][4];
    __shared__ float s_g[NPB][4];
    __shared__ float s_m0[NPB];
    __shared__ float s_redA[4][256];
    __shared__ float s_redB[4][256];
    int tid = threadIdx.x;
    int g = tid >> 6, lane = tid & 63;
    int base = blockIdx.x * NPB;      // 30000 = 1000*30 exactly
    if (tid < NPB) {
        int node = base + tid;
        float fr = 0.f;
#pragma unroll
        for (int t = 0; t < 16; t++) { float v = subH[node * 16 + t]; fr += v * v; }
        // A = -i * H * 1e-4/||H||_F  (eigen- and norm-clamps provably always fire
        // and their scalar factors cancel; Taylor >=2nd order terms are <=5e-9)
        float coef = 1e-4f * rsqrtf(fr);
#pragma unroll
        for (int s = 0; s < 4; s++) {
            s_g[tid][s]     = coef * subH[node * 16 + s] * sub_mask[node * 4 + s];
            s_nodes[tid][s] = sub_nodes[node * 4 + s];
        }
        s_m0[tid] = sub_mask[node * 4];
    }
    __syncthreads();
    float esc = *escp;
    float lsum[4] = {0.f, 0.f, 0.f, 0.f};
    float lsq[4]  = {0.f, 0.f, 0.f, 0.f};
    for (int j = g; j < NPB; j += 4) {
        int node = base + j;
        f16x8 hv[4];
#pragma unroll
        for (int s = 0; s < 4; s++)
            hv[s] = *reinterpret_cast<const f16x8*>(h + s_nodes[j][s] * 512 + lane * 8);
        float4 x4 = *reinterpret_cast<const float4*>(x + node * NC + lane * 4);
        float xr[4] = {x4.x, x4.y, x4.z, x4.w};
        float G[4] = {s_g[j][0], s_g[j][1], s_g[j][2], s_g[j][3]};
        float m0 = s_m0[j];
        f16x8 zo;
        float or4[4], oi4[4];
#pragma unroll
        for (int e = 0; e < 4; e++) {
            float hr0 = (float)hv[0][2 * e], hi0 = (float)hv[0][2 * e + 1];
            float er = m0 * hr0, ei = m0 * hi0;     // identity (self) term
#pragma unroll
            for (int s = 0; s < 4; s++) {
                float hr = (float)hv[s][2 * e], hi = (float)hv[s][2 * e + 1];
                er = fmaf(G[s], hi, er);            // -i*g*(hr+i*hi)
                ei = fmaf(-G[s], hr, ei);
            }
            float outr = fmaf(esc, er, xr[e]);
            float outi = esc * ei;
            or4[e] = outr; oi4[e] = outi;
            zo[2 * e] = (_Float16)outr; zo[2 * e + 1] = (_Float16)outi;
            float mag = sqrtf(fmaf(outr, outr, fmaf(outi, outi, 1e-5f)));
            mag = fminf(fmaxf(mag, 1e-5f), 1000.f);
            lsum[e] += mag;
            lsq[e] = fmaf(mag, mag, lsq[e]);
        }
        if (use_f16) {
            *reinterpret_cast<f16x8*>(zbuf + node * 512 + lane * 8) = zo;
        } else {
            *reinterpret_cast<float4*>(outz + node * 512 + lane * 4) =
                make_float4(or4[0], or4[1], or4[2], or4[3]);
            *reinterpret_cast<float4*>(outz + node * 512 + 256 + lane * 4) =
                make_float4(oi4[0], oi4[1], oi4[2], oi4[3]);
        }
    }
#pragma unroll
    for (int e = 0; e < 4; e++) {
        s_redA[g][lane * 4 + e] = lsum[e];
        s_redB[g][lane * 4 + e] = lsq[e];
    }
    __syncthreads();
    float a = s_redA[0][tid] + s_redA[1][tid] + s_redA[2][tid] + s_redA[3][tid];
    float b = s_redB[0][tid] + s_redB[1][tid] + s_redB[2][tid] + s_redB[3][tid];
    atomicAdd(&ssum[tid], a);      // tid == channel; 1000 adds per address
    atomicAdd(&ssumsq[tid], b);
}

// ---- layernorm + phase + leaky crelu; stats affine recomputed inline ----
__global__ __launch_bounds__(256) void k_norm(
    float* __restrict__ out, const _Float16* __restrict__ zbuf, int use_f16,
    const float* __restrict__ ssum, const float* __restrict__ ssumsq,
    const float* __restrict__ lnw, const float* __restrict__ lnb)
{
    int tid = threadIdx.x;
    int node = blockIdx.x * 4 + (tid >> 6);        // 7500 blocks
    int c0 = (tid & 63) * 4;
    float re[4], im[4];
    if (use_f16) {
        f16x8 z = *reinterpret_cast<const f16x8*>(zbuf + node * 512 + c0 * 2);
#pragma unroll
        for (int e = 0; e < 4; e++) { re[e] = (float)z[2 * e]; im[e] = (float)z[2 * e + 1]; }
    } else {
        float4 r4 = *reinterpret_cast<const float4*>(out + node * 512 + c0);
        float4 i4 = *reinterpret_cast<const float4*>(out + node * 512 + 256 + c0);
        re[0] = r4.x; re[1] = r4.y; re[2] = r4.z; re[3] = r4.w;
        im[0] = i4.x; im[1] = i4.y; im[2] = i4.z; im[3] = i4.w;
    }
    float4 s4 = *reinterpret_cast<const float4*>(ssum + c0);
    float4 q4 = *reinterpret_cast<const float4*>(ssumsq + c0);
    float4 w4 = *reinterpret_cast<const float4*>(lnw + c0);
    float4 lb4 = *reinterpret_cast<const float4*>(lnb + c0);
    float S[4] = {s4.x, s4.y, s4.z, s4.w};
    float Q[4] = {q4.x, q4.y, q4.z, q4.w};
    float W[4] = {w4.x, w4.y, w4.z, w4.w};
    float L[4] = {lb4.x, lb4.y, lb4.z, lb4.w};
    const float invN = 1.0f / (float)N_NODES;
    float orr[4], oii[4];
#pragma unroll
    for (int e = 0; e < 4; e++) {
        float mean = S[e] * invN;
        float var = fmaxf(Q[e] * invN - mean * mean, 0.f);
        float denom = sqrtf(var + 1e-5f) + 1e-5f;
        float A = fabsf(W[e]) / denom;
        float Bc = L[e] - mean * A;
        float r = re[e], i = im[e];
        float mag = sqrtf(fmaf(r, r, fmaf(i, i, 1e-5f)));
        mag = fminf(fmaxf(mag, 1e-5f), 1000.f);
        float sm = fmaf(mag, A, Bc);
        sm = fminf(fmaxf(sm, 1e-5f), 10.0f);
        float px = fminf(fmaxf(r, -1e6f), 1e6f) + 1e-10f;
        float py = fminf(fmaxf(i, -1e6f), 1e6f);
        float r2 = fmaf(px, px, py * py);
        float inv = rsqrtf(r2);
        float zr = sm * px * inv, zi = sm * py * inv;
        zr = fminf(fmaxf(zr, -5.f), 5.f);
        zi = fminf(fmaxf(zi, -5.f), 5.f);
        orr[e] = zr > 0.f ? zr : 0.01f * zr;
        oii[e] = zi > 0.f ? zi : 0.01f * zi;
    }
    *reinterpret_cast<float4*>(out + node * 512 + c0) =
        make_float4(orr[0], orr[1], orr[2], orr[3]);
    *reinterpret_cast<float4*>(out + node * 512 + 256 + c0) =
        make_float4(oii[0], oii[1], oii[2], oii[3]);
}

extern "C" void kernel_launch(void* const* d_in, const int* in_sizes, int n_in,
                              void* d_out, int out_size, void* d_ws, size_t ws_size,
                              hipStream_t stream) {
    const float* x        = (const float*)d_in[0];
    // d_in[1] edge_index: unused (sub_nodes/sub_mask/sub_H are precomputed)
    const int*   sub_nodes = (const int*)d_in[2];
    const float* sub_mask  = (const float*)d_in[3];
    const float* subH      = (const float*)d_in[4];
    const float* wr  = (const float*)d_in[5];
    const float* wi  = (const float*)d_in[6];
    const float* br  = (const float*)d_in[7];
    const float* bi  = (const float*)d_in[8];
    const float* lnw = (const float*)d_in[9];
    const float* lnb = (const float*)d_in[10];
    const float* esc = (const float*)d_in[11];
    float* out = (float*)d_out;

    char* ws = (char*)d_ws;
    const size_t XB_OFF   = 0;                    // 30000*256*2  = 15,360,000
    const size_t WB_OFF   = 15360000;             // 512*256*2    =    262,144
    const size_t H_OFF    = 15622144;             // 30000*512*2  = 30,720,000
    const size_t STAT_OFF = 46342144;             // 4 * 1024
    const size_t ZB_OFF   = 46346240;             // 30000*512*2  = 30,720,000 (optional)
    const size_t WS_NEED_F16 = ZB_OFF + 30720000; // 77,066,240
    _Float16* xb = (_Float16*)(ws + XB_OFF);
    _Float16* Wb = (_Float16*)(ws + WB_OFF);
    _Float16* h  = (_Float16*)(ws + H_OFF);
    float* ssum   = (float*)(ws + STAT_OFF);
    float* ssumsq = (float*)(ws + STAT_OFF + 1024);
    _Float16* zbuf = (_Float16*)(ws + ZB_OFF);
    int use_f16 = (ws_size >= WS_NEED_F16) ? 1 : 0;

    hipMemsetAsync(ssum, 0, 2048, stream);
    hipLaunchKernelGGL(k_conv_x, dim3(7500), dim3(256), 0, stream, x, xb);
    hipLaunchKernelGGL(k_conv_w, dim3(128), dim3(256), 0, stream, wr, wi, Wb);
    hipLaunchKernelGGL(k_gemm, dim3(235 * 2), dim3(256), 0, stream, xb, Wb, br, bi, h);
    hipLaunchKernelGGL(k_evolve, dim3(1000), dim3(256), 0, stream,
                       x, sub_nodes, sub_mask, subH, h, esc, out, zbuf, use_f16,
                       ssum, ssumsq);
    hipLaunchKernelGGL(k_norm, dim3(7500), dim3(256), 0, stream,
                       out, zbuf, use_f16, ssum, ssumsq, lnw, lnb);
}